// Round 4
// baseline (158.324 us; speedup 1.0000x reference)
//
#include <hip/hip_runtime.h>
#include <cstdint>

#define B_ROWS 32768
#define DIM    256
#define KCODES 1024
#define NSPLIT 2

typedef _Float16 f16x8 __attribute__((ext_vector_type(8)));
typedef float    f32x4 __attribute__((ext_vector_type(4)));

// ws layout:
//   [0, 512K)        cb_hi  (fp16, per-code 512B rows, 16B-granule XOR-swizzled)
//   [512K, 1M)       cb_lo  (fp16, scaled x2048, same swizzle)
//   [1M, 1M+4K)      inv_norm (float[1024])
//   [1M+4K, ...)     cand   (float2[NSPLIT][B_ROWS] = {dot, bitcast(k)})

// ---------------- prep: codebook -> fp16 hi/lo (swizzled) + 1/norm ----------------
__global__ __launch_bounds__(64) void vq_prep(const float* __restrict__ cb,
                                              _Float16* __restrict__ hi,
                                              _Float16* __restrict__ lo,
                                              float* __restrict__ inv_norm) {
  const int k = blockIdx.x;
  const int lane = threadIdx.x;
  float4 c = reinterpret_cast<const float4*>(cb)[k * 64 + lane];
  float nrm = c.x * c.x + c.y * c.y + c.z * c.z + c.w * c.w;
#pragma unroll
  for (int off = 32; off; off >>= 1) nrm += __shfl_xor(nrm, off);
  if (lane == 0) inv_norm[k] = 1.0f / nrm;

  float f[4] = {c.x, c.y, c.z, c.w};
  _Float16 h[4], l[4];
#pragma unroll
  for (int i = 0; i < 4; ++i) {
    h[i] = (_Float16)f[i];
    l[i] = (_Float16)((f[i] - (float)h[i]) * 2048.0f);
  }
  // granule swizzle: phys = g ^ (code & 15) within the code's 512B row
  const int phys = (lane >> 1) ^ (k & 15);
  const int byteoff = k * 512 + phys * 16 + (lane & 1) * 8;
  *reinterpret_cast<uint2*>((char*)hi + byteoff) = *reinterpret_cast<uint2*>(h);
  *reinterpret_cast<uint2*>((char*)lo + byteoff) = *reinterpret_cast<uint2*>(l);
}

__device__ __forceinline__ void gld16(const void* g, void* l) {
  __builtin_amdgcn_global_load_lds(
      (const __attribute__((address_space(1))) uint32_t*)g,
      (__attribute__((address_space(3))) uint32_t*)l, 16, 0, 0);
}

// ---------------- main: 64 rows/wave ILP kernel ----------------
// 1 wave/SIMD by design (A-frags = 256 VGPRs). Each 32B LDS read feeds 12 MFMAs.
// Acc double-buffer: epilogue(t) VALU overlaps MFMA(t+1). ~400 regs: cap MUST stay 512.
__global__ __launch_bounds__(256, 1) void vq_main(const float* __restrict__ emb,
                                                  const _Float16* __restrict__ cbh,
                                                  const _Float16* __restrict__ cbl,
                                                  const float* __restrict__ inv_g,
                                                  float2* __restrict__ cand) {
  __shared__ uint4 Btile[2][1024];   // 2 x 16KB tiles: [0,8K) hi, [8K,16K) lo
  __shared__ float inv_s[KCODES];

  const int flat = threadIdx.x;
  const int wave = flat >> 6;
  const int lane = flat & 63;
  const int quad = lane >> 4;
  const int lr   = lane & 15;

  const int split  = blockIdx.x & (NSPLIT - 1);
  const int rowblk = blockIdx.x >> 1;
  const int t0 = split * 32;         // 32 tiles of 16 codes = 512 codes per block

  reinterpret_cast<float4*>(inv_s)[flat] = reinterpret_cast<const float4*>(inv_g)[flat];

  // A fragments: 64 rows/wave (4 subtiles of 16), whole K-depth, hi+lo -> 256 VGPRs.
  f16x8 Ah[4][8], Al[4][8];
  const int row0 = rowblk * 256 + wave * 64;
#pragma unroll
  for (int s = 0; s < 4; ++s) {
    const float* rp = emb + (size_t)(row0 + s * 16 + lr) * DIM;
#pragma unroll
    for (int c = 0; c < 8; ++c) {
      const float* p = rp + c * 32 + quad * 8;
      float4 f0 = *reinterpret_cast<const float4*>(p);
      float4 f1 = *reinterpret_cast<const float4*>(p + 4);
      float f[8] = {f0.x, f0.y, f0.z, f0.w, f1.x, f1.y, f1.z, f1.w};
      f16x8 h, l;
#pragma unroll
      for (int j = 0; j < 8; ++j) {
        _Float16 hv = (_Float16)f[j];
        h[j] = hv;
        l[j] = (_Float16)((f[j] - (float)hv) * 2048.0f);
      }
      Ah[s][c] = h;
      Al[s][c] = l;
    }
  }

  auto stage = [&](int buf, int t) {
    const char* srcH = (const char*)cbh + t * 8192;
    const char* srcL = (const char*)cbl + t * 8192;
    char* dst = (char*)&Btile[buf][0];
    const int off = flat * 16;
    gld16(srcH + off,        dst + off);
    gld16(srcH + 4096 + off, dst + 4096 + off);
    gld16(srcL + off,        dst + 8192 + off);
    gld16(srcL + 4096 + off, dst + 12288 + off);
  };
  stage(0, t0);

  float bg[16], bd[16];
  int   bk[16];
#pragma unroll
  for (int i = 0; i < 16; ++i) { bg[i] = -1.0f; bd[i] = 0.0f; bk[i] = t0 * 16; }

  // compute one 16-code tile into a fresh acc set (96 MFMAs per call)
  auto comp = [&](const char* buf, f32x4* aA, f32x4* aB) {
#pragma unroll
    for (int s = 0; s < 4; ++s) {
      aA[s] = (f32x4){0, 0, 0, 0};
      aB[s] = (f32x4){0, 0, 0, 0};
    }
#pragma unroll
    for (int c = 0; c < 8; ++c) {
      const int g = (((c * 4 + quad) ^ lr) * 16) + lr * 512;  // de-swizzled granule
      f16x8 bh = *reinterpret_cast<const f16x8*>(buf + g);
      f16x8 bl = *reinterpret_cast<const f16x8*>(buf + 8192 + g);
#pragma unroll
      for (int s = 0; s < 4; ++s) {
        aA[s] = __builtin_amdgcn_mfma_f32_16x16x32_f16(Ah[s][c], bh, aA[s], 0, 0, 0);
        aB[s] = __builtin_amdgcn_mfma_f32_16x16x32_f16(Al[s][c], bh, aB[s], 0, 0, 0);
        aB[s] = __builtin_amdgcn_mfma_f32_16x16x32_f16(Ah[s][c], bl, aB[s], 0, 0, 0);
      }
    }
  };

  // argmax epilogue for a completed acc set (tile t); runs on VALU while the
  // other acc set's MFMAs are in flight (independent registers)
  auto epi = [&](const f32x4* aA, const f32x4* aB, int t) {
    const int n = t * 16 + lr;             // C/D layout: col = lane&15
    const float inl = inv_s[n];
#pragma unroll
    for (int s = 0; s < 4; ++s)
#pragma unroll
      for (int r = 0; r < 4; ++r) {
        float d = fmaf(aB[s][r], 4.8828125e-4f, aA[s][r]);   // + cross/2048
        float g = d * d * inl;
        const int i = (s << 2) | r;
        if (g > bg[i]) { bg[i] = g; bd[i] = d; bk[i] = n; }
      }
  };

  f32x4 aA0[4], aB0[4], aA1[4], aB1[4];
  for (int tt = 0; tt < 32; tt += 2) {
    __syncthreads();                        // tile tt ready in buf0
    stage(1, t0 + tt + 1);                  // tt+1 <= 31 always
    comp((const char*)&Btile[0][0], aA0, aB0);
    if (tt) epi(aA1, aB1, t0 + tt - 1);
    __syncthreads();                        // tile tt+1 ready in buf1
    if (tt + 2 < 32) stage(0, t0 + tt + 2);
    comp((const char*)&Btile[1][0], aA1, aB1);
    epi(aA0, aB0, t0 + tt);
  }
  epi(aA1, aB1, t0 + 31);

  // cross-lane argmax over 16 cols per quad; rows = row0 + s*16 + quad*4 + r
#pragma unroll
  for (int s = 0; s < 4; ++s) {
#pragma unroll
    for (int r = 0; r < 4; ++r) {
      const int i = (s << 2) | r;
      float g = bg[i]; int k = bk[i]; float d = bd[i];
#pragma unroll
      for (int m = 1; m < 16; m <<= 1) {
        float g2 = __shfl_xor(g, m);
        int   k2 = __shfl_xor(k, m);
        float d2 = __shfl_xor(d, m);
        if (g2 > g || (g2 == g && k2 < k)) { g = g2; k = k2; d = d2; }
      }
      if (lr == 0) {
        const int row = row0 + s * 16 + quad * 4 + r;
        cand[(size_t)split * B_ROWS + row] = make_float2(d, __int_as_float(k));
      }
    }
  }
}

// ---------------- reduce: pick best split candidate, write z + index ----------------
__global__ __launch_bounds__(256) void vq_reduce(const float2* __restrict__ cand,
                                                 const float* __restrict__ inv_g,
                                                 const float* __restrict__ cb,
                                                 float* __restrict__ out) {
  const int wave = threadIdx.x >> 6;
  const int lane = threadIdx.x & 63;
  const int row = blockIdx.x * 4 + wave;

  float best_g = -1.0f, best_d = 0.0f;
  int best_k = 0;
#pragma unroll
  for (int s = 0; s < NSPLIT; ++s) {
    float2 c = cand[(size_t)s * B_ROWS + row];
    int k = __float_as_int(c.y);
    float g = c.x * c.x * inv_g[k];
    if (g > best_g || (g == best_g && k < best_k)) {
      best_g = g; best_d = c.x; best_k = k;
    }
  }
  const float alpha = best_d * inv_g[best_k];
  float4 c4 = reinterpret_cast<const float4*>(cb)[best_k * 64 + lane];
  float4 z = {alpha * c4.x, alpha * c4.y, alpha * c4.z, alpha * c4.w};
  reinterpret_cast<float4*>(out)[(size_t)row * 64 + lane] = z;
  if (lane == 0) out[(size_t)B_ROWS * DIM + row] = (float)best_k;
}

extern "C" void kernel_launch(void* const* d_in, const int* in_sizes, int n_in,
                              void* d_out, int out_size, void* d_ws, size_t ws_size,
                              hipStream_t stream) {
  const float* emb = (const float*)d_in[0];
  const float* cb  = (const float*)d_in[1];
  _Float16* cbh = (_Float16*)d_ws;
  _Float16* cbl = (_Float16*)((char*)d_ws + (512 << 10));
  float*    inv = (float*)((char*)d_ws + (1 << 20));
  float2*   cand = (float2*)((char*)d_ws + (1 << 20) + 4096);

  vq_prep<<<KCODES, 64, 0, stream>>>(cb, cbh, cbl, inv);
  vq_main<<<(B_ROWS / 256) * NSPLIT, 256, 0, stream>>>(emb, cbh, cbl, inv, cand);
  vq_reduce<<<B_ROWS / 4, 256, 0, stream>>>(cand, inv, cb, (float*)d_out);
}

// Round 5
// 157.894 us; speedup vs baseline: 1.0027x; 1.0027x over previous
//
#include <hip/hip_runtime.h>
#include <cstdint>

#define B_ROWS 32768
#define DIM    256
#define KCODES 1024
#define NSPLIT 2

typedef _Float16 f16x8 __attribute__((ext_vector_type(8)));
typedef float    f32x4 __attribute__((ext_vector_type(4)));

// ws layout:
//   [0, 512K)        cbh  (fp16 NORMALIZED codebook hi, 512B/code, 16B-granule XOR-swizzled)
//   [512K, 1M)       cbl  (fp16 residual x2048, same swizzle)
//   [1M, 1M+4K)      ivs  (float[1024] = 1/||c||  — for alpha reconstruction)
//   [1M+4K, ...)     cand (float2[NSPLIT][B_ROWS] = {normalized dot, bitcast(k)})

// ---------------- prep: normalize codebook -> fp16 hi/lo (swizzled) + 1/||c|| ----------------
__global__ __launch_bounds__(64) void vq_prep(const float* __restrict__ cb,
                                              _Float16* __restrict__ hi,
                                              _Float16* __restrict__ lo,
                                              float* __restrict__ ivs) {
  const int k = blockIdx.x;
  const int lane = threadIdx.x;
  float4 c = reinterpret_cast<const float4*>(cb)[k * 64 + lane];
  float nrm = c.x * c.x + c.y * c.y + c.z * c.z + c.w * c.w;
#pragma unroll
  for (int off = 32; off; off >>= 1) nrm += __shfl_xor(nrm, off);
  const float invn = 1.0f / sqrtf(nrm);
  if (lane == 0) ivs[k] = invn;

  float f[4] = {c.x * invn, c.y * invn, c.z * invn, c.w * invn};
  _Float16 h[4], l[4];
#pragma unroll
  for (int i = 0; i < 4; ++i) {
    h[i] = (_Float16)f[i];
    l[i] = (_Float16)((f[i] - (float)h[i]) * 2048.0f);
  }
  // granule swizzle: phys = g ^ (code & 15) within the code's 512B row
  const int phys = (lane >> 1) ^ (k & 15);
  const int byteoff = k * 512 + phys * 16 + (lane & 1) * 8;
  *reinterpret_cast<uint2*>((char*)hi + byteoff) = *reinterpret_cast<uint2*>(h);
  *reinterpret_cast<uint2*>((char*)lo + byteoff) = *reinterpret_cast<uint2*>(l);
}

__device__ __forceinline__ void gld16(const void* g, void* l) {
  __builtin_amdgcn_global_load_lds(
      (const __attribute__((address_space(1))) uint32_t*)g,
      (__attribute__((address_space(3))) uint32_t*)l, 16, 0, 0);
}

// ---------------- main: 64 rows/wave, 3 independent acc sets, 32-code chunks ----------------
// 1 wave/SIMD (A-frags = 256 VGPRs). LDS = 64KB dbuf, 16 barriers/block.
// Normalized B: g = d*d, no inv lookup in the hot loop.
__global__ __launch_bounds__(256, 1) void vq_main(const float* __restrict__ emb,
                                                  const _Float16* __restrict__ cbh,
                                                  const _Float16* __restrict__ cbl,
                                                  float2* __restrict__ cand) {
  __shared__ uint4 Btile[2][2048];   // 2 x 32KB chunks: [t0 hi 8K][t0 lo 8K][t1 hi 8K][t1 lo 8K]

  const int flat = threadIdx.x;
  const int wave = flat >> 6;
  const int lane = flat & 63;
  const int quad = lane >> 4;
  const int lr   = lane & 15;

  const int split  = blockIdx.x & (NSPLIT - 1);
  const int rowblk = blockIdx.x >> 1;
  const int code0  = split * 512;    // 16 chunks of 32 codes

  // A fragments: 64 rows/wave (4 subtiles of 16), whole K-depth, hi+lo -> 256 VGPRs.
  f16x8 Ah[4][8], Al[4][8];
  const int row0 = rowblk * 256 + wave * 64;
#pragma unroll
  for (int s = 0; s < 4; ++s) {
    const float* rp = emb + (size_t)(row0 + s * 16 + lr) * DIM;
#pragma unroll
    for (int c = 0; c < 8; ++c) {
      const float* p = rp + c * 32 + quad * 8;
      float4 f0 = *reinterpret_cast<const float4*>(p);
      float4 f1 = *reinterpret_cast<const float4*>(p + 4);
      float f[8] = {f0.x, f0.y, f0.z, f0.w, f1.x, f1.y, f1.z, f1.w};
      f16x8 h, l;
#pragma unroll
      for (int j = 0; j < 8; ++j) {
        _Float16 hv = (_Float16)f[j];
        h[j] = hv;
        l[j] = (_Float16)((f[j] - (float)hv) * 2048.0f);
      }
      Ah[s][c] = h;
      Al[s][c] = l;
    }
  }

  // stage one 32-code chunk (32KB) into buf; 4 regions of 8KB (t0h,t0l,t1h,t1l),
  // each wave copies contiguous 2KB per region => dst = base + lane*16 pattern.
  auto stage = [&](int buf, int ch) {
    const int cbase = code0 + ch * 32;
    char* dst = (char*)&Btile[buf][0];
    const int off = wave * 2048 + lane * 16;
#pragma unroll
    for (int r = 0; r < 4; ++r) {
      const char* src = (const char*)((r & 1) ? cbl : cbh) + (cbase + (r >> 1) * 16) * 512;
      gld16(src + off,        dst + r * 8192 + off);
      gld16(src + off + 1024, dst + r * 8192 + off + 1024);
    }
  };
  stage(0, 0);

  float bg[16], bd[16];
  int   bk[16];
#pragma unroll
  for (int i = 0; i < 16; ++i) { bg[i] = -1.0f; bd[i] = 0.0f; bk[i] = code0; }

  __syncthreads();                    // chunk 0 staged
  for (int ch = 0; ch < 16; ++ch) {
    const char* base = (const char*)&Btile[ch & 1][0];
    if (ch + 1 < 16) stage((ch + 1) & 1, ch + 1);

#pragma unroll
    for (int tt = 0; tt < 2; ++tt) {
      f32x4 aA[4], aB[4], aC[4];
#pragma unroll
      for (int s = 0; s < 4; ++s) {
        aA[s] = (f32x4){0, 0, 0, 0};
        aB[s] = (f32x4){0, 0, 0, 0};
        aC[s] = (f32x4){0, 0, 0, 0};
      }
#pragma unroll
      for (int c = 0; c < 8; ++c) {
        const int g = (((c * 4 + quad) ^ lr) * 16) + lr * 512;  // de-swizzled granule
        f16x8 bh = *reinterpret_cast<const f16x8*>(base + tt * 16384 + g);
        f16x8 bl = *reinterpret_cast<const f16x8*>(base + tt * 16384 + 8192 + g);
        // 12 independent accumulator chains per c-iter: no back-to-back same-acc MFMAs
#pragma unroll
        for (int s = 0; s < 4; ++s)
          aA[s] = __builtin_amdgcn_mfma_f32_16x16x32_f16(Ah[s][c], bh, aA[s], 0, 0, 0);
#pragma unroll
        for (int s = 0; s < 4; ++s)
          aB[s] = __builtin_amdgcn_mfma_f32_16x16x32_f16(Al[s][c], bh, aB[s], 0, 0, 0);
#pragma unroll
        for (int s = 0; s < 4; ++s)
          aC[s] = __builtin_amdgcn_mfma_f32_16x16x32_f16(Ah[s][c], bl, aC[s], 0, 0, 0);
      }

      const int n = code0 + ch * 32 + tt * 16 + lr;   // C/D layout: col = lane&15
#pragma unroll
      for (int s = 0; s < 4; ++s)
#pragma unroll
        for (int r = 0; r < 4; ++r) {
          float x = aB[s][r] + aC[s][r];
          float d = fmaf(x, 4.8828125e-4f, aA[s][r]);  // d = hh + (lh+hl)/2048
          float g = d * d;                              // codebook normalized: g = dot^2
          const int i = (s << 2) | r;
          if (g > bg[i]) { bg[i] = g; bd[i] = d; bk[i] = n; }
        }
    }
    if (ch + 1 < 16) __syncthreads();   // waves done with buf; next stage drained
  }

  // cross-lane argmax over 16 cols per quad; rows = row0 + s*16 + quad*4 + r
#pragma unroll
  for (int s = 0; s < 4; ++s) {
#pragma unroll
    for (int r = 0; r < 4; ++r) {
      const int i = (s << 2) | r;
      float g = bg[i]; int k = bk[i]; float d = bd[i];
#pragma unroll
      for (int m = 1; m < 16; m <<= 1) {
        float g2 = __shfl_xor(g, m);
        int   k2 = __shfl_xor(k, m);
        float d2 = __shfl_xor(d, m);
        if (g2 > g || (g2 == g && k2 < k)) { g = g2; k = k2; d = d2; }
      }
      if (lr == 0) {
        const int row = row0 + s * 16 + quad * 4 + r;
        cand[(size_t)split * B_ROWS + row] = make_float2(d, __int_as_float(k));
      }
    }
  }
}

// ---------------- reduce: pick best split candidate, write z + index ----------------
__global__ __launch_bounds__(256) void vq_reduce(const float2* __restrict__ cand,
                                                 const float* __restrict__ ivs,
                                                 const float* __restrict__ cb,
                                                 float* __restrict__ out) {
  const int wave = threadIdx.x >> 6;
  const int lane = threadIdx.x & 63;
  const int row = blockIdx.x * 4 + wave;

  float best_g = -1.0f, best_d = 0.0f;
  int best_k = 0;
#pragma unroll
  for (int s = 0; s < NSPLIT; ++s) {
    float2 c = cand[(size_t)s * B_ROWS + row];
    int k = __float_as_int(c.y);
    float g = c.x * c.x;                 // d is normalized dot: g = d^2
    if (g > best_g || (g == best_g && k < best_k)) {
      best_g = g; best_d = c.x; best_k = k;
    }
  }
  // alpha = dot/||c||^2 = d_norm / ||c|| = d_norm * ivs[k]
  const float alpha = best_d * ivs[best_k];
  float4 c4 = reinterpret_cast<const float4*>(cb)[best_k * 64 + lane];
  float4 z = {alpha * c4.x, alpha * c4.y, alpha * c4.z, alpha * c4.w};
  reinterpret_cast<float4*>(out)[(size_t)row * 64 + lane] = z;
  if (lane == 0) out[(size_t)B_ROWS * DIM + row] = (float)best_k;
}

extern "C" void kernel_launch(void* const* d_in, const int* in_sizes, int n_in,
                              void* d_out, int out_size, void* d_ws, size_t ws_size,
                              hipStream_t stream) {
  const float* emb = (const float*)d_in[0];
  const float* cb  = (const float*)d_in[1];
  _Float16* cbh = (_Float16*)d_ws;
  _Float16* cbl = (_Float16*)((char*)d_ws + (512 << 10));
  float*    ivs = (float*)((char*)d_ws + (1 << 20));
  float2*   cand = (float2*)((char*)d_ws + (1 << 20) + 4096);

  vq_prep<<<KCODES, 64, 0, stream>>>(cb, cbh, cbl, ivs);
  vq_main<<<(B_ROWS / 256) * NSPLIT, 256, 0, stream>>>(emb, cbh, cbl, cand);
  vq_reduce<<<B_ROWS / 4, 256, 0, stream>>>(cand, ivs, cb, (float*)d_out);
}

// Round 6
// 153.714 us; speedup vs baseline: 1.0300x; 1.0272x over previous
//
#include <hip/hip_runtime.h>
#include <cstdint>

#define B_ROWS 32768
#define DIM    256
#define KCODES 1024
#define NSPLIT 2

typedef _Float16 f16x8  __attribute__((ext_vector_type(8)));
typedef float    f32x16 __attribute__((ext_vector_type(16)));

// ws layout:
// [0, 1M):     codebook fp16 hi/lo (NORMALIZED), tile-major: 32 tiles(32 codes) x 32KB.
//              tile = [j=0: hi 8K | lo 8K][j=1: hi 8K | lo 8K]   (depth halves j: [0,128),[128,256))
//              within a plane: code n at n*256B; 16B granules swizzled phys = g ^ (n&15)
// [1M, +4K):   ivs[1024] = 1/||c||
// [1M+4K, ..): cand float2[NSPLIT][B_ROWS] = {normalized dot, bitcast(k)}

// ---------------- prep: normalize codebook -> fp16 hi/lo (swizzled planes) ----------------
__global__ __launch_bounds__(64) void vq_prep(const float* __restrict__ cb,
                                              char* __restrict__ cbq,
                                              float* __restrict__ ivs) {
  const int k = blockIdx.x;
  const int lane = threadIdx.x;
  float4 c = reinterpret_cast<const float4*>(cb)[k * 64 + lane];
  float nrm = c.x * c.x + c.y * c.y + c.z * c.z + c.w * c.w;
#pragma unroll
  for (int off = 32; off; off >>= 1) nrm += __shfl_xor(nrm, off);
  const float invn = 1.0f / sqrtf(nrm);
  if (lane == 0) ivs[k] = invn;

  float f[4] = {c.x * invn, c.y * invn, c.z * invn, c.w * invn};
  _Float16 h[4], l[4];
#pragma unroll
  for (int i = 0; i < 4; ++i) {
    h[i] = (_Float16)f[i];
    l[i] = (_Float16)((f[i] - (float)h[i]) * 2048.0f);
  }
  // lane covers depth elems [lane*4, lane*4+4) = half of granule g=lane>>1
  const int g = lane >> 1;            // global granule [0,32), 8 elems each
  const int jd = g >> 4;              // depth half
  const int gl = g & 15;              // granule local to half
  const int phys = gl ^ (k & 15);
  char* base = cbq + (size_t)(k >> 5) * 32768 + jd * 16384 +
               (k & 31) * 256 + phys * 16 + (lane & 1) * 8;
  *reinterpret_cast<uint2*>(base)        = *reinterpret_cast<uint2*>(h);  // hi plane
  *reinterpret_cast<uint2*>(base + 8192) = *reinterpret_cast<uint2*>(l);  // lo plane
}

__device__ __forceinline__ void gld16(const void* g, void* l) {
  __builtin_amdgcn_global_load_lds(
      (const __attribute__((address_space(1))) uint32_t*)g,
      (__attribute__((address_space(3))) uint32_t*)l, 16, 0, 0);
}

// ---------------- main: 32x32x16 MFMA, 2-wave blocks (4 blocks/CU), depth-halved dbuf ----------------
// Block = 128 thr = 2 waves = 64 rows. 4 independent barrier domains per CU.
// A (32 rows, hi+lo) = 128 VGPRs; acc 48; live ~245 -> cap 256 via (128,2).
__global__ __launch_bounds__(128, 2) void vq_main(const float* __restrict__ emb,
                                                  const char* __restrict__ cbq,
                                                  float2* __restrict__ cand) {
  __shared__ uint4 Btile[2][1024];   // 2 x 16KB: one depth-half (hi 8K | lo 8K)

  const int flat = threadIdx.x;
  const int wave = flat >> 6;
  const int lane = flat & 63;
  const int n    = lane & 31;        // MFMA 32x32: col / own-row index
  const int hh   = lane >> 5;        // k-half within lane

  const int split  = blockIdx.x & (NSPLIT - 1);
  const int rowblk = blockIdx.x >> 1;
  const int code0  = split * 512;    // 16 tiles of 32 codes
  const int row0   = rowblk * 64 + wave * 32;

  // A fragments: 32 rows/wave, full depth, hi+lo. A[m=lane&31][k=c*16+hh*8+j].
  f16x8 Ah[16], Al[16];
  {
    const float* rp = emb + (size_t)(row0 + n) * DIM;
#pragma unroll
    for (int c = 0; c < 16; ++c) {
      const float* p = rp + c * 16 + hh * 8;
      float4 f0 = *reinterpret_cast<const float4*>(p);
      float4 f1 = *reinterpret_cast<const float4*>(p + 4);
      float f[8] = {f0.x, f0.y, f0.z, f0.w, f1.x, f1.y, f1.z, f1.w};
      f16x8 hv, lv;
#pragma unroll
      for (int j = 0; j < 8; ++j) {
        _Float16 t = (_Float16)f[j];
        hv[j] = t;
        lv[j] = (_Float16)((f[j] - (float)t) * 2048.0f);
      }
      Ah[c] = hv;
      Al[c] = lv;
    }
  }

  // stage one 16KB depth-half chunk: idx = tile*2 + j
  auto stage = [&](int buf, int idx) {
    const char* src = cbq + (size_t)(code0 / 32 + (idx >> 1)) * 32768 + (idx & 1) * 16384;
    char* dst = (char*)&Btile[buf][0];
    const int off = flat * 16;       // 128 thr x 16B = 2KB per region
#pragma unroll
    for (int r = 0; r < 8; ++r)
      gld16(src + r * 2048 + off, dst + r * 2048 + off);
  };
  stage(0, 0);

  float bd[16];
  int   bk[16];
#pragma unroll
  for (int i = 0; i < 16; ++i) { bd[i] = 0.0f; bk[i] = code0; }

  __syncthreads();                   // chunk 0 staged
  for (int t = 0; t < 16; ++t) {
    f32x16 aA = {}, aB = {}, aC = {};
#pragma unroll
    for (int j = 0; j < 2; ++j) {
      const int idx = t * 2 + j;
      if (idx + 1 < 32) stage((idx + 1) & 1, idx + 1);
      const char* base = (const char*)&Btile[idx & 1][0];
#pragma unroll
      for (int c = 0; c < 8; ++c) {
        const int xg = ((c * 2 + hh) ^ n) & 15;      // de-swizzled granule
        const int a  = n * 256 + xg * 16;
        f16x8 bh = *reinterpret_cast<const f16x8*>(base + a);
        f16x8 bl = *reinterpret_cast<const f16x8*>(base + 8192 + a);
        const int cg = j * 8 + c;
        aA = __builtin_amdgcn_mfma_f32_32x32x16_f16(Ah[cg], bh, aA, 0, 0, 0);
        aB = __builtin_amdgcn_mfma_f32_32x32x16_f16(Al[cg], bh, aB, 0, 0, 0);
        aC = __builtin_amdgcn_mfma_f32_32x32x16_f16(Ah[cg], bl, aC, 0, 0, 0);
      }
      if (idx + 1 < 32) __syncthreads();
    }
    // epilogue: C/D layout col=lane&31, row=(r&3)+8*(r>>2)+4*(lane>>5)
    const int nc = code0 + t * 32 + n;
#pragma unroll
    for (int r = 0; r < 16; ++r) {
      float d = fmaf(aB[r] + aC[r], 4.8828125e-4f, aA[r]);   // d = hh + (lh+hl)/2048
      float g = d * d;                                        // normalized codebook
      if (g > bd[r] * bd[r]) { bd[r] = d; bk[r] = nc; }
    }
  }

  // cross-lane argmax over the 32 cols within each half-wave lane group
#pragma unroll
  for (int r = 0; r < 16; ++r) {
    float d = bd[r]; int k = bk[r];
#pragma unroll
    for (int m = 1; m < 32; m <<= 1) {
      float d2 = __shfl_xor(d, m);
      int   k2 = __shfl_xor(k, m);
      float g = d * d, g2 = d2 * d2;
      if (g2 > g || (g2 == g && k2 < k)) { d = d2; k = k2; }
    }
    if (n == 0) {
      const int row = row0 + (r & 3) + 8 * (r >> 2) + 4 * hh;
      cand[(size_t)split * B_ROWS + row] = make_float2(d, __int_as_float(k));
    }
  }
}

// ---------------- reduce: pick best split candidate, write z + index ----------------
__global__ __launch_bounds__(256) void vq_reduce(const float2* __restrict__ cand,
                                                 const float* __restrict__ ivs,
                                                 const float* __restrict__ cb,
                                                 float* __restrict__ out) {
  const int wave = threadIdx.x >> 6;
  const int lane = threadIdx.x & 63;
  const int row = blockIdx.x * 4 + wave;

  float best_d = 0.0f;
  int best_k = KCODES;
#pragma unroll
  for (int s = 0; s < NSPLIT; ++s) {
    float2 c = cand[(size_t)s * B_ROWS + row];
    int k = __float_as_int(c.y);
    float g = c.x * c.x, gb = best_d * best_d;
    if (g > gb || (g == gb && k < best_k)) { best_d = c.x; best_k = k; }
  }
  // alpha = dot/||c||^2 = d_norm * (1/||c||)
  const float alpha = best_d * ivs[best_k];
  float4 c4 = reinterpret_cast<const float4*>(cb)[best_k * 64 + lane];
  float4 z = {alpha * c4.x, alpha * c4.y, alpha * c4.z, alpha * c4.w};
  reinterpret_cast<float4*>(out)[(size_t)row * 64 + lane] = z;
  if (lane == 0) out[(size_t)B_ROWS * DIM + row] = (float)best_k;
}

extern "C" void kernel_launch(void* const* d_in, const int* in_sizes, int n_in,
                              void* d_out, int out_size, void* d_ws, size_t ws_size,
                              hipStream_t stream) {
  const float* emb = (const float*)d_in[0];
  const float* cb  = (const float*)d_in[1];
  char*   cbq  = (char*)d_ws;
  float*  ivs  = (float*)((char*)d_ws + (1 << 20));
  float2* cand = (float2*)((char*)d_ws + (1 << 20) + 4096);

  vq_prep<<<KCODES, 64, 0, stream>>>(cb, cbq, ivs);
  vq_main<<<(B_ROWS / 64) * NSPLIT, 128, 0, stream>>>(emb, cbq, cand);
  vq_reduce<<<B_ROWS / 4, 256, 0, stream>>>(cand, ivs, cb, (float*)d_out);
}